// Round 7
// baseline (380.831 us; speedup 1.0000x reference)
//
#include <hip/hip_runtime.h>
#include <math.h>

// DecoderCell (LFADS) on MI355X — round 7: register-direct bf16 MFMA GEMM
// (no LDS, no barriers) for the PRE path. Each wave owns a 32x64 output tile,
// loads A/B fragments straight to VGPRs, K-loop fully unrolled. W reuse via
// L1 (4 row-stacked waves/block load identical W), A reuse via L2 (XCD swz).
//
// PRE pipeline: pre_h/pre_w/pre_fw -> con_r -> con_zn -> co -> gen_r ->
//               gen_zn -> fac   (9 dispatches)
// Scratch liveness (PRE):
//   rh_C : out f32 [256:384) (bf16) — con_r -> con_zn, dead before gen_zn
//   cs_b : out f32 [384:512) (bf16 con_state) — con_zn -> co
//   gi_b : out f32 [1152:1216) (bf16) — co -> gen_r/gen_zn, dead before fac
//   rh_G : ws panel cols [512:1024) — gen_r -> gen_zn
// Fallback (no ws): round-5/6 LDS drain kernels, unchanged.

#define HD    1280
#define NROW  16384
#define CLIPV 5.0f

typedef float  f32x4  __attribute__((ext_vector_type(4)));
typedef __bf16 bf16x8 __attribute__((ext_vector_type(8)));
typedef short  s16x8  __attribute__((ext_vector_type(8)));
typedef unsigned short u16;

// ws layout (bf16 element offsets). Panel: [16384][1024] =
//   cols [0:512) h_gen | [512:768) h_con | [768:896) factor | [896:1024) x
#define OFF_CW   16777216
#define OFF_CWH  (OFF_CW  + 196608)
#define OFF_COW  (OFF_CWH + 196608)
#define OFF_GWI  (OFF_COW + 65536)
#define OFF_GWH  (OFF_GWI + 196608)
#define OFF_FW   (OFF_GWH + 786432)
#define WS_ELEMS (OFF_FW  + 65536)

__device__ __forceinline__ unsigned short f2bf(float f) {
    unsigned u = __float_as_uint(f);
    u = u + 0x7fffu + ((u >> 16) & 1u);
    return (unsigned short)(u >> 16);
}
__device__ __forceinline__ float sigm(float v) { return 1.0f / (1.0f + __expf(-v)); }

__device__ __forceinline__ int xswz() {
    const int b   = blockIdx.x;
    const int cpx = gridDim.x >> 3;
    return (b & 7) * cpx + (b >> 3);
}

// =================== register-direct GEMM core (PRE path) ===================
struct RSrc {                 // element(row, kabs) = p[s] + row*ld[s] + kabs
    const u16* p[5];          // pointers pre-adjusted so kabs indexes directly
    int        ld[5];         // (chunk s = kabs >> 7)
};

template <int NT>             // NT = K/32 steps
__device__ __forceinline__ void rgemm(f32x4 (&acc)[2][4],
                                      const RSrc& A, const RSrc& W,
                                      int arow, int wcol) {
    const int l   = threadIdx.x & 63;
    const int r15 = l & 15;
    const int g8  = (l >> 4) << 3;
#pragma unroll
    for (int kt = 0; kt < NT; ++kt) {
        const int s  = kt >> 2;                    // static chunk index
        const int kk = (kt << 5) + g8;             // absolute k offset
        bf16x8 a[2], b[4];
#pragma unroll
        for (int f = 0; f < 2; ++f)
            a[f] = *(const bf16x8*)(A.p[s] + (size_t)(arow + f * 16 + r15) * A.ld[s] + kk);
#pragma unroll
        for (int j = 0; j < 4; ++j)
            b[j] = *(const bf16x8*)(W.p[s] + (size_t)(wcol + j * 16 + r15) * W.ld[s] + kk);
#pragma unroll
        for (int f = 0; f < 2; ++f)
#pragma unroll
            for (int j = 0; j < 4; ++j)
                acc[f][j] = __builtin_amdgcn_mfma_f32_16x16x32_bf16(a[f], b[j], acc[f][j], 0, 0, 0);
    }
}

// f32 A-operand variant (fac: A = gen_state f32 in out)
template <int NT>
__device__ __forceinline__ void rgemm_f32a(f32x4 (&acc)[2][4],
                                           const float* Ap, int Ald,
                                           const RSrc& W, int arow, int wcol) {
    const int l   = threadIdx.x & 63;
    const int r15 = l & 15;
    const int g8  = (l >> 4) << 3;
#pragma unroll
    for (int kt = 0; kt < NT; ++kt) {
        const int s  = kt >> 2;
        const int kk = (kt << 5) + g8;
        bf16x8 a[2], b[4];
#pragma unroll
        for (int f = 0; f < 2; ++f) {
            const float* p = Ap + (size_t)(arow + f * 16 + r15) * Ald + kk;
            float4 u0 = *(const float4*)(p + 0);
            float4 u1 = *(const float4*)(p + 4);
            const float ff[8] = {u0.x, u0.y, u0.z, u0.w, u1.x, u1.y, u1.z, u1.w};
            s16x8 v;
#pragma unroll
            for (int q = 0; q < 8; ++q) v[q] = (short)f2bf(ff[q]);
            a[f] = __builtin_bit_cast(bf16x8, v);
        }
#pragma unroll
        for (int j = 0; j < 4; ++j)
            b[j] = *(const bf16x8*)(W.p[s] + (size_t)(wcol + j * 16 + r15) * W.ld[s] + kk);
#pragma unroll
        for (int f = 0; f < 2; ++f)
#pragma unroll
            for (int j = 0; j < 4; ++j)
                acc[f][j] = __builtin_amdgcn_mfma_f32_16x16x32_bf16(a[f], b[j], acc[f][j], 0, 0, 0);
    }
}

// reg-core epilogue indices: block = 128 rows x 64 cols, wave w owns rows w*32+
#define REPILOGUE_IDX                                                       \
    const int l    = threadIdx.x & 63;                                      \
    const int w    = threadIdx.x >> 6;                                      \
    const int arow = w * 32;

// =================== legacy LDS core (fallback path) ========================
__device__ __forceinline__ void gll16(const void* g, void* l) {
    __builtin_amdgcn_global_load_lds((const __attribute__((address_space(1))) void*)g,
                                     (__attribute__((address_space(3))) void*)l,
                                     16, 0, 0);
}

struct KSrc {
    const void* p[5];
    int ld[5];
    int kind[5];
    const float* scale;
};

template <int R>
__device__ __forceinline__ void stage_issue(char* tile, const KSrc& S, int rbase,
                                            int k0, int sIdx, float* regs) {
    const int tid = threadIdx.x;
    if (S.kind[sIdx]) {
        const char* base = (const char*)S.p[sIdx];
        const int w = tid >> 6;
        const size_t ld = (size_t)S.ld[sIdx];
#pragma unroll
        for (int e = 0; e < R / 32; ++e) {
            const int q = e * 256 + tid;
            const int r = q >> 3;
            const int b = ((q & 7) << 4) ^ ((r & 7) << 4);
            const char* g = base + ((size_t)(rbase + r) * ld + k0) * 2 + b;
            gll16(g, tile + e * 4096 + w * 1024);
        }
    } else {
        const float* base = (const float*)S.p[sIdx];
        const size_t ld = (size_t)S.ld[sIdx];
#pragma unroll
        for (int e = 0; e < R / 64; ++e) {
            const int q = e * 256 + tid;
            const int r = q >> 2;
            const int kloc = (q & 3) << 4;
            const float* pp = base + (size_t)(rbase + r) * ld + k0 + kloc;
            float* d = regs + e * 16;
            *(float4*)(d + 0)  = *(const float4*)(pp + 0);
            *(float4*)(d + 4)  = *(const float4*)(pp + 4);
            *(float4*)(d + 8)  = *(const float4*)(pp + 8);
            *(float4*)(d + 12) = *(const float4*)(pp + 12);
        }
    }
}

template <int R>
__device__ __forceinline__ void stage_write(char* tile, const KSrc& S, int rbase,
                                            int k0, int sIdx, float* regs) {
    if (S.kind[sIdx]) return;
    const int tid = threadIdx.x;
#pragma unroll
    for (int e = 0; e < R / 64; ++e) {
        const int q = e * 256 + tid;
        const int r = q >> 2;
        float* ff = regs + e * 16;
        if (S.scale) {
            const int kabs = k0 + ((q & 3) << 4);
#pragma unroll
            for (int j = 0; j < 16; ++j) ff[j] *= S.scale[kabs + j];
        }
        s16x8 v0, v1;
#pragma unroll
        for (int j = 0; j < 8; ++j) {
            v0[j] = (short)f2bf(ff[j]);
            v1[j] = (short)f2bf(ff[j + 8]);
        }
        const int swz = (r & 7) << 4;
        *(s16x8*)(tile + r * 128 + ((((q & 3) << 5) + 0)  ^ swz)) = v0;
        *(s16x8*)(tile + r * 128 + ((((q & 3) << 5) + 16) ^ swz)) = v1;
    }
}

__device__ __forceinline__ bf16x8 ldfrag(const char* lds, int r, int ks, int g) {
    const char* p = lds + r * 128 + ((((ks << 2) + g) << 4) ^ ((r & 7) << 4));
    return __builtin_bit_cast(bf16x8, *(const s16x8*)p);
}

__device__ __forceinline__ void compute_tile64(f32x4 (&acc)[2][4],
                                               const char* At, const char* Wt) {
    const int l   = threadIdx.x & 63;
    const int w   = threadIdx.x >> 6;
    const int wr  = (w >> 1) << 5;
    const int wc  = (w & 1) << 6;
    const int g   = l >> 4;
    const int r15 = l & 15;
#pragma unroll
    for (int ks = 0; ks < 2; ++ks) {
        bf16x8 a[2], b[4];
#pragma unroll
        for (int f = 0; f < 2; ++f) a[f] = ldfrag(At, wr + f * 16 + r15, ks, g);
#pragma unroll
        for (int f = 0; f < 4; ++f) b[f] = ldfrag(Wt, wc + f * 16 + r15, ks, g);
#pragma unroll
        for (int i = 0; i < 2; ++i)
#pragma unroll
            for (int j = 0; j < 4; ++j)
                acc[i][j] = __builtin_amdgcn_mfma_f32_16x16x32_bf16(a[i], b[j], acc[i][j], 0, 0, 0);
    }
}

template <int NT>
__device__ __forceinline__ void gemm1(f32x4 (&acc)[2][4], char* At, char* Wt,
                                      const KSrc& A, const KSrc& W,
                                      int row0, int col0) {
    float ra[16], rw[32];
#pragma unroll
    for (int kt = 0; kt < NT; ++kt) {
        const int s = kt >> 1;
        __syncthreads();
        stage_issue<64> (At, A, row0, kt * 64, s, ra);
        stage_issue<128>(Wt, W, col0, kt * 64, s, rw);
        stage_write<64> (At, A, row0, kt * 64, s, ra);
        stage_write<128>(Wt, W, col0, kt * 64, s, rw);
        __syncthreads();
        compute_tile64(acc, At, Wt);
    }
}

#define GEMM_SHARED  __shared__ alignas(16) char At[8192], Wt[16384];
#define EPILOGUE_IDX                                                        \
    const int l  = threadIdx.x & 63;                                        \
    const int w  = threadIdx.x >> 6;                                        \
    const int wr = (w >> 1) << 5;                                           \
    const int wc = (w & 1) << 6;

// ---------------------------------------------------------- preconversion ---
__global__ __launch_bounds__(256) void k_pre_h(const float* __restrict__ x,
                                               const float* __restrict__ h0,
                                               u16* __restrict__ wsh) {
#pragma unroll
    for (int e = 0; e < 4; ++e) {
        const int q   = blockIdx.x * 1024 + e * 256 + threadIdx.x;
        const int row = q >> 7;
        const int c8  = (q & 127) << 3;
        const float* src;
        if (c8 < 768)      src = h0 + (size_t)row * HD + c8;
        else if (c8 < 896) src = h0 + (size_t)row * HD + c8 + 384;  // factor
        else               src = x + (size_t)row * 128 + (c8 - 896);
        float4 f0 = *(const float4*)(src + 0);
        float4 f1 = *(const float4*)(src + 4);
        const float ff[8] = {f0.x, f0.y, f0.z, f0.w, f1.x, f1.y, f1.z, f1.w};
        s16x8 v;
#pragma unroll
        for (int j = 0; j < 8; ++j) v[j] = (short)f2bf(ff[j]);
        *(s16x8*)(wsh + (size_t)row * 1024 + c8) = v;
    }
}

__global__ __launch_bounds__(256) void k_pre_w(const float* __restrict__ cw,
                                               const float* __restrict__ cwh,
                                               const float* __restrict__ cow,
                                               const float* __restrict__ gwi,
                                               const float* __restrict__ gwh,
                                               u16* __restrict__ dst) {
    const int q = blockIdx.x * 256 + threadIdx.x;
    const size_t eo = (size_t)q * 8;
    const float* src;
    if      (eo < 196608) src = cw  + eo;
    else if (eo < 393216) src = cwh + (eo - 196608);
    else if (eo < 458752) src = cow + (eo - 393216);
    else if (eo < 655360) src = gwi + (eo - 458752);
    else                  src = gwh + (eo - 655360);
    float4 f0 = *(const float4*)(src + 0);
    float4 f1 = *(const float4*)(src + 4);
    const float ff[8] = {f0.x, f0.y, f0.z, f0.w, f1.x, f1.y, f1.z, f1.w};
    s16x8 v;
#pragma unroll
    for (int j = 0; j < 8; ++j) v[j] = (short)f2bf(ff[j]);
    *(s16x8*)(dst + eo) = v;
}

__global__ __launch_bounds__(256) void k_pre_fw(const float* __restrict__ fw,
                                                u16* __restrict__ dst) {
    const int col = blockIdx.x * 256 + threadIdx.x;
    float s = 0.f;
    for (int r = 0; r < 128; ++r) {
        float a = fw[r * 512 + col];
        s = fmaf(a, a, s);
    }
    const float inv = 1.0f / fmaxf(sqrtf(s), 1e-12f);
    for (int r = 0; r < 128; ++r)
        dst[r * 512 + col] = f2bf(fw[r * 512 + col] * inv);
}

// ------------------------------------------------------------------ con_r ---
template <bool PRE>
__global__ __launch_bounds__(256) void k_con_r(
    const float* __restrict__ x, const float* __restrict__ h0,
    const float* __restrict__ wih, const float* __restrict__ bih,
    const float* __restrict__ whh, const float* __restrict__ bhh,
    const u16* __restrict__ ws, float* __restrict__ out) {
    const int lb = xswz();
    u16* outs = (u16*)out;
    if constexpr (PRE) {
        const int col0 = (lb & 3) * 64;
        const int row0 = (lb >> 2) * 128;
        RSrc A = {{ws + 896, ws + 640, ws + 256, ws + 256, nullptr},
                  {1024, 1024, 1024, 1024, 0}};
        RSrc W = {{ws + OFF_CW + 65536, ws + OFF_CW + 65536,
                   ws + OFF_CWH + 65536 - 256, ws + OFF_CWH + 65536 - 256, nullptr},
                  {256, 256, 256, 256, 0}};
        f32x4 acc[2][4] = {};
        REPILOGUE_IDX
        rgemm<16>(acc, A, W, row0 + arow, col0);
#pragma unroll
        for (int f = 0; f < 2; ++f)
#pragma unroll
            for (int j = 0; j < 4; ++j)
#pragma unroll
                for (int t = 0; t < 4; ++t) {
                    int row = row0 + arow + f * 16 + (l >> 4) * 4 + t;
                    int c   = col0 + j * 16 + (l & 15);
                    float rv = sigm(acc[f][j][t] + bih[256 + c] + bhh[256 + c]);
                    float hv = h0[(size_t)row * HD + 512 + c];
                    outs[(size_t)row * 2560 + 512 + c] = f2bf(rv * hv);  // rh_C
                }
    } else {
        GEMM_SHARED
        const int col0 = (lb & 1) * 128;
        const int row0 = (lb >> 1) * 64;
        KSrc A = {{x, h0 + 1024, h0 + 256, h0 + 256, nullptr},
                  {128, HD, HD, HD, 0}, {0, 0, 0, 0, 0}, nullptr};
        KSrc W = {{wih + 65536, wih + 65536, whh + 65536 - 256, whh + 65536 - 256, nullptr},
                  {256, 256, 256, 256, 0}, {0, 0, 0, 0, 0}, nullptr};
        f32x4 acc[2][4] = {};
        gemm1<8>(acc, At, Wt, A, W, row0, col0);
        EPILOGUE_IDX
#pragma unroll
        for (int i = 0; i < 2; ++i)
#pragma unroll
            for (int j = 0; j < 4; ++j)
#pragma unroll
                for (int t = 0; t < 4; ++t) {
                    int row = row0 + wr + i * 16 + (l >> 4) * 4 + t;
                    int c   = col0 + wc + j * 16 + (l & 15);
                    float rv = sigm(acc[i][j][t] + bih[256 + c] + bhh[256 + c]);
                    float hv = h0[(size_t)row * HD + 512 + c];
                    outs[(size_t)row * 2560 + 512 + c] = f2bf(rv * hv);
                }
    }
}

// ----------------------------------------------------------------- con_zn ---
template <bool PRE>
__global__ __launch_bounds__(256) void k_con_zn(
    const float* __restrict__ x, const float* __restrict__ h0,
    const float* __restrict__ wih, const float* __restrict__ bih,
    const float* __restrict__ whh, const float* __restrict__ bhh,
    const u16* __restrict__ ws, float* __restrict__ out) {
    const int lb = xswz();
    const u16* outsr = (const u16*)out;
    u16* outw = (u16*)out;
    if constexpr (PRE) {
        const int col0 = (lb & 3) * 64;
        const int row0 = (lb >> 2) * 128;
        RSrc Az = {{ws + 896, ws + 640, ws + 256, ws + 256, nullptr},
                   {1024, 1024, 1024, 1024, 0}};
        RSrc Wz = {{ws + OFF_CW, ws + OFF_CW, ws + OFF_CWH - 256, ws + OFF_CWH - 256, nullptr},
                   {256, 256, 256, 256, 0}};
        RSrc An = {{ws + 896, ws + 640, outsr + 256, outsr + 256, nullptr},
                   {1024, 1024, 2560, 2560, 0}};
        RSrc Wn = {{ws + OFF_CW + 512 * 256, ws + OFF_CW + 512 * 256,
                    ws + OFF_CWH + 512 * 256 - 256, ws + OFF_CWH + 512 * 256 - 256, nullptr},
                   {256, 256, 256, 256, 0}};
        f32x4 aZ[2][4] = {}, aN[2][4] = {};
        REPILOGUE_IDX
        rgemm<16>(aZ, Az, Wz, row0 + arow, col0);
        rgemm<16>(aN, An, Wn, row0 + arow, col0);
#pragma unroll
        for (int f = 0; f < 2; ++f)
#pragma unroll
            for (int j = 0; j < 4; ++j)
#pragma unroll
                for (int t = 0; t < 4; ++t) {
                    int row = row0 + arow + f * 16 + (l >> 4) * 4 + t;
                    int c   = col0 + j * 16 + (l & 15);
                    float zv = sigm(aZ[f][j][t] + bih[c] + bhh[c]);
                    float nv = tanhf(aN[f][j][t] + bih[512 + c] + bhh[512 + c]);
                    float hv = h0[(size_t)row * HD + 512 + c];
                    float hp = zv * hv + (1.0f - zv) * nv;
                    hp = fminf(fmaxf(hp, -CLIPV), CLIPV);
                    out[(size_t)row * HD + 512 + c] = hp;
                    outw[(size_t)row * 2560 + 768 + c] = f2bf(hp);     // cs_b
                }
    } else {
        GEMM_SHARED
        const int col0 = (lb & 1) * 128;
        const int row0 = (lb >> 1) * 64;
        KSrc Az = {{x, h0 + 1024, h0 + 256, h0 + 256, nullptr},
                   {128, HD, HD, HD, 0}, {0, 0, 0, 0, 0}, nullptr};
        KSrc Wz = {{wih, wih, whh - 256, whh - 256, nullptr},
                   {256, 256, 256, 256, 0}, {0, 0, 0, 0, 0}, nullptr};
        KSrc An = {{x, h0 + 1024, outsr + 256, outsr + 256, nullptr},
                   {128, HD, 2560, 2560, 0}, {0, 0, 1, 1, 0}, nullptr};
        KSrc Wn = {{wih + 512 * 256, wih + 512 * 256,
                    whh + 512 * 256 - 256, whh + 512 * 256 - 256, nullptr},
                   {256, 256, 256, 256, 0}, {0, 0, 0, 0, 0}, nullptr};
        f32x4 aZ[2][4] = {}, aN[2][4] = {};
        gemm1<8>(aZ, At, Wt, Az, Wz, row0, col0);
        gemm1<8>(aN, At, Wt, An, Wn, row0, col0);
        EPILOGUE_IDX
#pragma unroll
        for (int i = 0; i < 2; ++i)
#pragma unroll
            for (int j = 0; j < 4; ++j)
#pragma unroll
                for (int t = 0; t < 4; ++t) {
                    int row = row0 + wr + i * 16 + (l >> 4) * 4 + t;
                    int c   = col0 + wc + j * 16 + (l & 15);
                    float zv = sigm(aZ[i][j][t] + bih[c] + bhh[c]);
                    float nv = tanhf(aN[i][j][t] + bih[512 + c] + bhh[512 + c]);
                    float hv = h0[(size_t)row * HD + 512 + c];
                    float hp = zv * hv + (1.0f - zv) * nv;
                    out[(size_t)row * HD + 512 + c] = fminf(fmaxf(hp, -CLIPV), CLIPV);
                }
    }
}

// --------------------------------------------------------------------- co ---
template <bool PRE>
__global__ __launch_bounds__(256) void k_co(
    const float* __restrict__ cw, const float* __restrict__ cb,
    const u16* __restrict__ ws, float* __restrict__ out) {
    const int lb = xswz();
    u16* outw = (u16*)out;
    if constexpr (PRE) {
        const int col0 = (lb & 3) * 64;
        const int row0 = (lb >> 2) * 128;
        const u16* outsr = (const u16*)out;
        RSrc A = {{outsr + 768, outsr + 768, nullptr, nullptr, nullptr},
                  {2560, 2560, 0, 0, 0}};                              // cs_b
        RSrc W = {{ws + OFF_COW, ws + OFF_COW, nullptr, nullptr, nullptr},
                  {256, 256, 0, 0, 0}};
        f32x4 acc[2][4] = {};
        REPILOGUE_IDX
        rgemm<8>(acc, A, W, row0 + arow, col0);
#pragma unroll
        for (int f = 0; f < 2; ++f)
#pragma unroll
            for (int j = 0; j < 4; ++j)
#pragma unroll
                for (int t = 0; t < 4; ++t) {
                    int row = row0 + arow + f * 16 + (l >> 4) * 4 + t;
                    int c   = col0 + j * 16 + (l & 15);
                    float v = acc[f][j][t] + cb[c];
                    if (c < 128) {
                        out[(size_t)row * HD + 1024 + c]    = v;       // gen_input
                        outw[(size_t)row * 2560 + 2304 + c] = f2bf(v); // gi_b
                        out[(size_t)row * HD + 768 + c]     = v;       // mean out
                    } else {
                        out[(size_t)row * HD + 896 + (c - 128)] = v;   // logstd
                    }
                }
    } else {
        GEMM_SHARED
        const int col0 = (lb & 1) * 128;
        const int row0 = (lb >> 1) * 64;
        KSrc A = {{out + 512, out + 512, nullptr, nullptr, nullptr},
                  {HD, HD, 0, 0, 0}, {0, 0, 0, 0, 0}, nullptr};
        KSrc W = {{cw, cw, nullptr, nullptr, nullptr},
                  {256, 256, 0, 0, 0}, {0, 0, 0, 0, 0}, nullptr};
        f32x4 acc[2][4] = {};
        gemm1<4>(acc, At, Wt, A, W, row0, col0);
        EPILOGUE_IDX
#pragma unroll
        for (int i = 0; i < 2; ++i)
#pragma unroll
            for (int j = 0; j < 4; ++j)
#pragma unroll
                for (int t = 0; t < 4; ++t) {
                    int row = row0 + wr + i * 16 + (l >> 4) * 4 + t;
                    int c   = col0 + wc + j * 16 + (l & 15);
                    float v = acc[i][j][t] + cb[c];
                    if (c < 128) {
                        out[(size_t)row * HD + 1024 + c]    = v;
                        outw[(size_t)row * 2560 + 2304 + c] = f2bf(v);
                    }
                }
    }
}

// ------------------------------------------------------------------ gen_r ---
template <bool PRE>
__global__ __launch_bounds__(256) void k_gen_r(
    const float* __restrict__ h0,
    const float* __restrict__ wih, const float* __restrict__ bih,
    const float* __restrict__ whh, const float* __restrict__ bhh,
    u16* __restrict__ ws, float* __restrict__ out) {
    const int lb = xswz();
    const u16* outsr = (const u16*)out;
    u16* outw = (u16*)out;
    if constexpr (PRE) {
        const int col0 = (lb & 7) * 64;
        const int row0 = (lb >> 3) * 128;
        RSrc A = {{outsr + 2304, ws - 128, ws - 128, ws - 128, ws - 128},
                  {2560, 1024, 1024, 1024, 1024}};
        RSrc W = {{ws + OFF_GWI + 65536, ws + OFF_GWH + 512 * 512 - 128,
                   ws + OFF_GWH + 512 * 512 - 128, ws + OFF_GWH + 512 * 512 - 128,
                   ws + OFF_GWH + 512 * 512 - 128},
                  {128, 512, 512, 512, 512}};
        f32x4 acc[2][4] = {};
        REPILOGUE_IDX
        rgemm<20>(acc, A, W, row0 + arow, col0);
#pragma unroll
        for (int f = 0; f < 2; ++f)
#pragma unroll
            for (int j = 0; j < 4; ++j)
#pragma unroll
                for (int t = 0; t < 4; ++t) {
                    int row = row0 + arow + f * 16 + (l >> 4) * 4 + t;
                    int c   = col0 + j * 16 + (l & 15);
                    float rv = sigm(acc[f][j][t] + bih[512 + c] + bhh[512 + c]);
                    float hv = h0[(size_t)row * HD + c];
                    ws[(size_t)row * 1024 + 512 + c] = f2bf(rv * hv);  // rh_G
                }
    } else {
        GEMM_SHARED
        const int col0 = (lb & 3) * 128;
        const int row0 = (lb >> 2) * 64;
        KSrc A = {{outsr + 2304, h0 - 128, h0 - 128, h0 - 128, h0 - 128},
                  {2560, HD, HD, HD, HD}, {1, 0, 0, 0, 0}, nullptr};
        KSrc W = {{wih + 65536, whh + 512 * 512 - 128, whh + 512 * 512 - 128,
                   whh + 512 * 512 - 128, whh + 512 * 512 - 128},
                  {128, 512, 512, 512, 512}, {0, 0, 0, 0, 0}, nullptr};
        f32x4 acc[2][4] = {};
        gemm1<10>(acc, At, Wt, A, W, row0, col0);
        EPILOGUE_IDX
#pragma unroll
        for (int i = 0; i < 2; ++i)
#pragma unroll
            for (int j = 0; j < 4; ++j)
#pragma unroll
                for (int t = 0; t < 4; ++t) {
                    int row = row0 + wr + i * 16 + (l >> 4) * 4 + t;
                    int c   = col0 + wc + j * 16 + (l & 15);
                    float rv = sigm(acc[i][j][t] + bih[512 + c] + bhh[512 + c]);
                    float hv = h0[(size_t)row * HD + c];
                    outw[(size_t)row * 2560 + 1536 + c] = f2bf(rv * hv);
                }
    }
}

// ----------------------------------------------------------------- gen_zn ---
template <bool PRE>
__global__ __launch_bounds__(256) void k_gen_zn(
    const float* __restrict__ h0,
    const float* __restrict__ wih, const float* __restrict__ bih,
    const float* __restrict__ whh, const float* __restrict__ bhh,
    const u16* __restrict__ ws, float* __restrict__ out) {
    const int lb = xswz();
    const u16* outsr = (const u16*)out;
    if constexpr (PRE) {
        const int col0 = (lb & 7) * 64;
        const int row0 = (lb >> 3) * 128;
        RSrc Az = {{outsr + 2304, ws - 128, ws - 128, ws - 128, ws - 128},
                   {2560, 1024, 1024, 1024, 1024}};
        RSrc Wz = {{ws + OFF_GWI, ws + OFF_GWH - 128, ws + OFF_GWH - 128,
                    ws + OFF_GWH - 128, ws + OFF_GWH - 128},
                   {128, 512, 512, 512, 512}};
        RSrc An = {{outsr + 2304, ws + 384, ws + 384, ws + 384, ws + 384},
                   {2560, 1024, 1024, 1024, 1024}};
        RSrc Wn = {{ws + OFF_GWI + 1024 * 128, ws + OFF_GWH + 1024 * 512 - 128,
                    ws + OFF_GWH + 1024 * 512 - 128, ws + OFF_GWH + 1024 * 512 - 128,
                    ws + OFF_GWH + 1024 * 512 - 128},
                   {128, 512, 512, 512, 512}};
        f32x4 aZ[2][4] = {}, aN[2][4] = {};
        REPILOGUE_IDX
        rgemm<20>(aZ, Az, Wz, row0 + arow, col0);
        rgemm<20>(aN, An, Wn, row0 + arow, col0);
#pragma unroll
        for (int f = 0; f < 2; ++f)
#pragma unroll
            for (int j = 0; j < 4; ++j)
#pragma unroll
                for (int t = 0; t < 4; ++t) {
                    int row = row0 + arow + f * 16 + (l >> 4) * 4 + t;
                    int c   = col0 + j * 16 + (l & 15);
                    float zv = sigm(aZ[f][j][t] + bih[c] + bhh[c]);
                    float nv = tanhf(aN[f][j][t] + bih[1024 + c] + bhh[1024 + c]);
                    float hv = h0[(size_t)row * HD + c];
                    float hp = zv * hv + (1.0f - zv) * nv;
                    out[(size_t)row * HD + c] = fminf(fmaxf(hp, -CLIPV), CLIPV);
                }
    } else {
        GEMM_SHARED
        const int col0 = (lb & 3) * 128;
        const int row0 = (lb >> 2) * 64;
        KSrc Az = {{outsr + 2304, h0 - 128, h0 - 128, h0 - 128, h0 - 128},
                   {2560, HD, HD, HD, HD}, {1, 0, 0, 0, 0}, nullptr};
        KSrc Wz = {{wih, whh - 128, whh - 128, whh - 128, whh - 128},
                   {128, 512, 512, 512, 512}, {0, 0, 0, 0, 0}, nullptr};
        KSrc An = {{outsr + 2304, outsr + 1408, outsr + 1408, outsr + 1408, outsr + 1408},
                   {2560, 2560, 2560, 2560, 2560}, {1, 1, 1, 1, 1}, nullptr};
        KSrc Wn = {{wih + 1024 * 128, whh + 1024 * 512 - 128, whh + 1024 * 512 - 128,
                    whh + 1024 * 512 - 128, whh + 1024 * 512 - 128},
                   {128, 512, 512, 512, 512}, {0, 0, 0, 0, 0}, nullptr};
        f32x4 aZ[2][4] = {}, aN[2][4] = {};
        gemm1<10>(aZ, At, Wt, Az, Wz, row0, col0);
        gemm1<10>(aN, At, Wt, An, Wn, row0, col0);
        EPILOGUE_IDX
#pragma unroll
        for (int i = 0; i < 2; ++i)
#pragma unroll
            for (int j = 0; j < 4; ++j)
#pragma unroll
                for (int t = 0; t < 4; ++t) {
                    int row = row0 + wr + i * 16 + (l >> 4) * 4 + t;
                    int c   = col0 + wc + j * 16 + (l & 15);
                    float zv = sigm(aZ[i][j][t] + bih[c] + bhh[c]);
                    float nv = tanhf(aN[i][j][t] + bih[1024 + c] + bhh[1024 + c]);
                    float hv = h0[(size_t)row * HD + c];
                    float hp = zv * hv + (1.0f - zv) * nv;
                    out[(size_t)row * HD + c] = fminf(fmaxf(hp, -CLIPV), CLIPV);
                }
    }
}

// -------------------------------------------------------------------- fac ---
template <bool PRE>
__global__ __launch_bounds__(256) void k_fac(
    const float* __restrict__ fw,
    const u16* __restrict__ ws, float* __restrict__ out) {
    const int lb = xswz();
    if constexpr (PRE) {
        const int col0 = (lb & 1) * 64;
        const int row0 = (lb >> 1) * 128;
        RSrc W = {{ws + OFF_FW, ws + OFF_FW, ws + OFF_FW, ws + OFF_FW, nullptr},
                  {512, 512, 512, 512, 0}};
        f32x4 acc[2][4] = {};
        REPILOGUE_IDX
        rgemm_f32a<16>(acc, out, HD, W, row0 + arow, col0);
#pragma unroll
        for (int f = 0; f < 2; ++f)
#pragma unroll
            for (int j = 0; j < 4; ++j)
#pragma unroll
                for (int t = 0; t < 4; ++t) {
                    int row = row0 + arow + f * 16 + (l >> 4) * 4 + t;
                    int c   = col0 + j * 16 + (l & 15);
                    out[(size_t)row * HD + 1152 + c] = acc[f][j][t];
                }
    } else {
        GEMM_SHARED
        __shared__ float invn[512];
        const int row0 = lb * 64;
        const int t = threadIdx.x;
        float s0 = 0.f, s1 = 0.f;
        for (int r = 0; r < 128; ++r) {
            float a0 = fw[r * 512 + t];
            float a1 = fw[r * 512 + t + 256];
            s0 = fmaf(a0, a0, s0);
            s1 = fmaf(a1, a1, s1);
        }
        invn[t]       = 1.0f / fmaxf(sqrtf(s0), 1e-12f);
        invn[t + 256] = 1.0f / fmaxf(sqrtf(s1), 1e-12f);
        __syncthreads();
        KSrc A = {{out, out, out, out, nullptr},
                  {HD, HD, HD, HD, 0}, {0, 0, 0, 0, 0}, nullptr};
        KSrc W = {{fw, fw, fw, fw, nullptr},
                  {512, 512, 512, 512, 0}, {0, 0, 0, 0, 0}, invn};
        f32x4 acc[2][4] = {};
        gemm1<8>(acc, At, Wt, A, W, row0, 0);
        EPILOGUE_IDX
#pragma unroll
        for (int i = 0; i < 2; ++i)
#pragma unroll
            for (int j = 0; j < 4; ++j)
#pragma unroll
                for (int tt = 0; tt < 4; ++tt) {
                    int row = row0 + wr + i * 16 + (l >> 4) * 4 + tt;
                    int c   = wc + j * 16 + (l & 15);
                    out[(size_t)row * HD + 1152 + c] = acc[i][j][tt];
                }
    }
}

// --------------------------------------------------- co_fin (fallback only) --
__global__ __launch_bounds__(256) void k_co_fin(
    const float* __restrict__ cw, const float* __restrict__ cb,
    float* __restrict__ out) {
    GEMM_SHARED
    const int row0 = xswz() * 64;
    KSrc A = {{out + 512, out + 512, nullptr, nullptr, nullptr},
              {HD, HD, 0, 0, 0}, {0, 0, 0, 0, 0}, nullptr};
    KSrc W = {{cw + 128 * 256, cw + 128 * 256, nullptr, nullptr, nullptr},
              {256, 256, 0, 0, 0}, {0, 0, 0, 0, 0}, nullptr};
    f32x4 acc[2][4] = {};
    gemm1<4>(acc, At, Wt, A, W, row0, 0);
    EPILOGUE_IDX
#pragma unroll
    for (int i = 0; i < 2; ++i)
#pragma unroll
        for (int j = 0; j < 4; ++j)
#pragma unroll
            for (int t = 0; t < 4; ++t) {
                int row = row0 + wr + i * 16 + (l >> 4) * 4 + t;
                int c   = wc + j * 16 + (l & 15);
                out[(size_t)row * HD + 896 + c] = acc[i][j][t] + cb[128 + c];
            }
#pragma unroll
    for (int e = 0; e < 8; ++e) {
        int idx = threadIdx.x + e * 256;
        int r   = idx >> 5;
        int cc  = (idx & 31) << 2;
        *(float4*)&out[(size_t)(row0 + r) * HD + 768 + cc] =
            *(const float4*)&out[(size_t)(row0 + r) * HD + 1024 + cc];
    }
}

// ----------------------------------------------------------------- launch ---
extern "C" void kernel_launch(void* const* d_in, const int* in_sizes, int n_in,
                              void* d_out, int out_size, void* d_ws, size_t ws_size,
                              hipStream_t stream) {
    const float* x    = (const float*)d_in[0];
    const float* h0   = (const float*)d_in[1];
    const float* cwih = (const float*)d_in[2];
    const float* cbih = (const float*)d_in[3];
    const float* cwhh = (const float*)d_in[4];
    const float* cbhh = (const float*)d_in[5];
    const float* cow  = (const float*)d_in[6];
    const float* cob  = (const float*)d_in[7];
    const float* gwih = (const float*)d_in[8];
    const float* gbih = (const float*)d_in[9];
    const float* gwhh = (const float*)d_in[10];
    const float* gbhh = (const float*)d_in[11];
    const float* fw   = (const float*)d_in[12];
    float* out = (float*)d_out;
    u16* ws = (u16*)d_ws;

    const bool pre = (ws_size >= (size_t)WS_ELEMS * 2);
    if (pre) {
        k_pre_h <<<2048, 256, 0, stream>>>(x, h0, ws);
        k_pre_w <<<704,  256, 0, stream>>>(cwih, cwhh, cow, gwih, gwhh, ws + OFF_CW);
        k_pre_fw<<<2,    256, 0, stream>>>(fw, ws + OFF_FW);
        k_con_r <true><<<512,  256, 0, stream>>>(x, h0, cwih, cbih, cwhh, cbhh, ws, out);
        k_con_zn<true><<<512,  256, 0, stream>>>(x, h0, cwih, cbih, cwhh, cbhh, ws, out);
        k_co    <true><<<512,  256, 0, stream>>>(cow, cob, ws, out);
        k_gen_r <true><<<1024, 256, 0, stream>>>(h0, gwih, gbih, gwhh, gbhh, ws, out);
        k_gen_zn<true><<<1024, 256, 0, stream>>>(h0, gwih, gbih, gwhh, gbhh, ws, out);
        k_fac   <true><<<256,  256, 0, stream>>>(fw, ws, out);
    } else {
        k_con_r <false><<<512,  256, 0, stream>>>(x, h0, cwih, cbih, cwhh, cbhh, nullptr, out);
        k_con_zn<false><<<512,  256, 0, stream>>>(x, h0, cwih, cbih, cwhh, cbhh, nullptr, out);
        k_co    <false><<<512,  256, 0, stream>>>(cow, cob, nullptr, out);
        k_gen_r <false><<<1024, 256, 0, stream>>>(h0, gwih, gbih, gwhh, gbhh, nullptr, out);
        k_gen_zn<false><<<1024, 256, 0, stream>>>(h0, gwih, gbih, gwhh, gbhh, nullptr, out);
        k_fac   <false><<<256,  256, 0, stream>>>(fw, nullptr, out);
        k_co_fin<<<256, 256, 0, stream>>>(cow, cob, out);
    }
}

// Round 8
// 203.980 us; speedup vs baseline: 1.8670x; 1.8670x over previous
//
#include <hip/hip_runtime.h>
#include <math.h>

// DecoderCell (LFADS) on MI355X — round 8: ONE fused persistent-block kernel.
// Block = 64 rows, 512 threads (8 waves), runs con_r -> con_zn -> co ->
// gen_r -> gen_zn -> fac with ALL intermediates in LDS:
//   rh_C (32K) / cs (32K) in R0 -> later rh_G (64K, full R0); gi (16K) in R1.
// gs (gen_state bf16, needed by fac) goes to the dead panel cols [512:1024).
// Staging: counted-vmcnt double-buffered global_load_lds (round-6 verified
// core), pre-swizzled sources, setprio(1) around MFMA.
// LDS map (163840 B): SA[0,16K) A-dbuf | SW[16K,80K) W-dbuf | R0[80K,144K) |
// R1[144K,160K).  Grid 256 = 1 block/CU exactly (no tail).

#define HD    1280
#define NROW  16384
#define CLIPV 5.0f

typedef float  f32x4  __attribute__((ext_vector_type(4)));
typedef __bf16 bf16x8 __attribute__((ext_vector_type(8)));
typedef short  s16x8  __attribute__((ext_vector_type(8)));
typedef unsigned short u16;

// ws layout (bf16 elements). Panel [16384][1024]:
//   cols [0:512) h_gen | [512:768) h_con | [768:896) factor | [896:1024) x
//   (cols [512:1024) are reused for gs after the con/co stages are done)
#define OFF_CW   16777216
#define OFF_CWH  (OFF_CW  + 196608)
#define OFF_COW  (OFF_CWH + 196608)
#define OFF_GWI  (OFF_COW + 65536)
#define OFF_GWH  (OFF_GWI + 196608)
#define OFF_FW   (OFF_GWH + 786432)
#define WS_ELEMS (OFF_FW  + 65536)

__device__ __forceinline__ unsigned short f2bf(float f) {
    unsigned u = __float_as_uint(f);
    u = u + 0x7fffu + ((u >> 16) & 1u);
    return (unsigned short)(u >> 16);
}
__device__ __forceinline__ float bf2f(u16 v) {
    return __uint_as_float(((unsigned)v) << 16);
}
__device__ __forceinline__ float sigm(float v) { return 1.0f / (1.0f + __expf(-v)); }

__device__ __forceinline__ int xswz() {
    const int b   = blockIdx.x;
    const int cpx = gridDim.x >> 3;
    return (b & 7) * cpx + (b >> 3);
}

__device__ __forceinline__ void gll16(const void* g, void* l) {
    __builtin_amdgcn_global_load_lds((const __attribute__((address_space(1))) void*)g,
                                     (__attribute__((address_space(3))) void*)l,
                                     16, 0, 0);
}

// swizzled LDS tile helpers (tile = R rows x 64 k bf16, row stride 128 B,
// 16B-slot XOR swizzle slot ^= (row&7))
__device__ __forceinline__ bf16x8 ldfrag(const char* lds, int r, int ks, int g) {
    const char* p = lds + r * 128 + ((((ks << 2) + g) << 4) ^ ((r & 7) << 4));
    return __builtin_bit_cast(bf16x8, *(const s16x8*)p);
}
__device__ __forceinline__ void ldsw16(char* tile, int r, int kloc, u16 v) {
    const int byte = r * 128 + ((((kloc >> 3) << 4) ^ ((r & 7) << 4)) + ((kloc & 7) << 1));
    *(u16*)(tile + byte) = v;
}

// ===================== fused-kernel staging (512 threads) ====================
__device__ __forceinline__ void stA(char* tile, const u16* p) {          // 64x64, ld=1024
    const int tid = threadIdx.x;
    const int r   = tid >> 3;
    const int b   = ((tid & 7) << 4) ^ ((r & 7) << 4);
    gll16((const char*)p + (size_t)r * 2048 + b, tile + (tid >> 6) * 1024);
}
__device__ __forceinline__ void stW(char* tile, const u16* p, int ld) {  // 256x64
    const int tid = threadIdx.x;
    const int w   = tid >> 6;
#pragma unroll
    for (int e = 0; e < 4; ++e) {
        const int q = e * 512 + tid;
        const int r = q >> 3;
        const int b = ((q & 7) << 4) ^ ((r & 7) << 4);
        gll16((const char*)p + (size_t)r * ld * 2 + b, tile + e * 8192 + w * 1024);
    }
}
__device__ __forceinline__ void stW128(char* tile, const u16* p, int ld) { // 128x64
    const int tid = threadIdx.x;
    const int w   = tid >> 6;
#pragma unroll
    for (int e = 0; e < 2; ++e) {
        const int q = e * 512 + tid;
        const int r = q >> 3;
        const int b = ((q & 7) << 4) ^ ((r & 7) << 4);
        gll16((const char*)p + (size_t)r * ld * 2 + b, tile + e * 8192 + w * 1024);
    }
}

// ===================== fused-kernel compute (8 waves) ========================
// waves: wr=(w>>2)*32 (2 row groups), wc=(w&3)*64 (4 col groups) -> 64x256
__device__ __forceinline__ void cmp256(f32x4 (&acc)[2][4], const char* At, const char* Wt) {
    const int l = threadIdx.x & 63, w = threadIdx.x >> 6;
    const int wr = (w >> 2) << 5, wc = (w & 3) << 6;
    const int g = l >> 4, r15 = l & 15;
#pragma unroll
    for (int ks = 0; ks < 2; ++ks) {
        bf16x8 a[2], b[4];
#pragma unroll
        for (int f = 0; f < 2; ++f) a[f] = ldfrag(At, wr + f * 16 + r15, ks, g);
#pragma unroll
        for (int j = 0; j < 4; ++j) b[j] = ldfrag(Wt, wc + j * 16 + r15, ks, g);
#pragma unroll
        for (int f = 0; f < 2; ++f)
#pragma unroll
            for (int j = 0; j < 4; ++j)
                acc[f][j] = __builtin_amdgcn_mfma_f32_16x16x32_bf16(a[f], b[j], acc[f][j], 0, 0, 0);
    }
}
// N=128 variant: wc=(w&3)*32, per wave 32x32
__device__ __forceinline__ void cmp128(f32x4 (&acc)[2][2], const char* At, const char* Wt) {
    const int l = threadIdx.x & 63, w = threadIdx.x >> 6;
    const int wr = (w >> 2) << 5, wc = (w & 3) << 5;
    const int g = l >> 4, r15 = l & 15;
#pragma unroll
    for (int ks = 0; ks < 2; ++ks) {
        bf16x8 a[2], b[2];
#pragma unroll
        for (int f = 0; f < 2; ++f) a[f] = ldfrag(At, wr + f * 16 + r15, ks, g);
#pragma unroll
        for (int j = 0; j < 2; ++j) b[j] = ldfrag(Wt, wc + j * 16 + r15, ks, g);
#pragma unroll
        for (int f = 0; f < 2; ++f)
#pragma unroll
            for (int j = 0; j < 2; ++j)
                acc[f][j] = __builtin_amdgcn_mfma_f32_16x16x32_bf16(a[f], b[j], acc[f][j], 0, 0, 0);
    }
}

// ===================== counted-vmcnt pass drivers ============================
// passS: A staged from panel (1 load) + W staged (4 loads) -> vmcnt(5)
template <int NT>
__device__ __forceinline__ void passS256(f32x4 (&acc)[2][4], char* SA, char* SW,
        const u16* panel, const int (&Ac)[NT],
        const u16* const (&Wp)[NT], const int (&Wld)[NT]) {
    stA(SA, panel + Ac[0]);
    stW(SW, Wp[0], Wld[0]);
#pragma unroll
    for (int kt = 0; kt < NT; ++kt) {
        const char* Acur = SA + (kt & 1) * 8192;
        const char* Wcur = SW + (kt & 1) * 32768;
        if (kt + 1 < NT) {
            stA(SA + ((kt + 1) & 1) * 8192, panel + Ac[kt + 1]);
            stW(SW + ((kt + 1) & 1) * 32768, Wp[kt + 1], Wld[kt + 1]);
            asm volatile("s_waitcnt vmcnt(5)" ::: "memory");
        } else {
            asm volatile("s_waitcnt vmcnt(0)" ::: "memory");
        }
        __builtin_amdgcn_s_barrier();
        __builtin_amdgcn_sched_barrier(0);
        __builtin_amdgcn_s_setprio(1);
        cmp256(acc, Acur, Wcur);
        __builtin_amdgcn_s_setprio(0);
        __builtin_amdgcn_s_barrier();
    }
}
// passR: A resident in LDS, W staged (4 loads) -> vmcnt(4)
template <int NT>
__device__ __forceinline__ void passR256(f32x4 (&acc)[2][4], char* SW,
        const char* const (&Ares)[NT],
        const u16* const (&Wp)[NT], const int (&Wld)[NT]) {
    stW(SW, Wp[0], Wld[0]);
#pragma unroll
    for (int kt = 0; kt < NT; ++kt) {
        const char* Wcur = SW + (kt & 1) * 32768;
        if (kt + 1 < NT) {
            stW(SW + ((kt + 1) & 1) * 32768, Wp[kt + 1], Wld[kt + 1]);
            asm volatile("s_waitcnt vmcnt(4)" ::: "memory");
        } else {
            asm volatile("s_waitcnt vmcnt(0)" ::: "memory");
        }
        __builtin_amdgcn_s_barrier();
        __builtin_amdgcn_sched_barrier(0);
        __builtin_amdgcn_s_setprio(1);
        cmp256(acc, Ares[kt], Wcur);
        __builtin_amdgcn_s_setprio(0);
        __builtin_amdgcn_s_barrier();
    }
}
// fac: A staged (1) + W128 staged (2) -> vmcnt(3)
template <int NT>
__device__ __forceinline__ void passS128(f32x4 (&acc)[2][2], char* SA, char* SW,
        const u16* panel, const int (&Ac)[NT],
        const u16* const (&Wp)[NT], const int (&Wld)[NT]) {
    stA(SA, panel + Ac[0]);
    stW128(SW, Wp[0], Wld[0]);
#pragma unroll
    for (int kt = 0; kt < NT; ++kt) {
        const char* Acur = SA + (kt & 1) * 8192;
        const char* Wcur = SW + (kt & 1) * 32768;
        if (kt + 1 < NT) {
            stA(SA + ((kt + 1) & 1) * 8192, panel + Ac[kt + 1]);
            stW128(SW + ((kt + 1) & 1) * 32768, Wp[kt + 1], Wld[kt + 1]);
            asm volatile("s_waitcnt vmcnt(3)" ::: "memory");
        } else {
            asm volatile("s_waitcnt vmcnt(0)" ::: "memory");
        }
        __builtin_amdgcn_s_barrier();
        __builtin_amdgcn_sched_barrier(0);
        __builtin_amdgcn_s_setprio(1);
        cmp128(acc, Acur, Wcur);
        __builtin_amdgcn_s_setprio(0);
        __builtin_amdgcn_s_barrier();
    }
}

// ============================ the fused kernel ===============================
__global__ __launch_bounds__(512, 1) void k_fused(
    const u16* __restrict__ ws, u16* __restrict__ wsw,
    const float* __restrict__ cbih, const float* __restrict__ cbhh,
    const float* __restrict__ cob,
    const float* __restrict__ gbih, const float* __restrict__ gbhh,
    float* __restrict__ out)
{
    __shared__ char LDS[163840];
    char* SA = LDS;                     // 2 x 8 KB
    char* SW = LDS + 16384;             // 2 x 32 KB
    char* R0 = LDS + 81920;             // 64 KB
    char* R1 = LDS + 147456;            // 16 KB

    const int row0 = blockIdx.x * 64;
    const u16* panel = ws + (size_t)row0 * 1024;
    const u16* wcw  = ws + OFF_CW;
    const u16* wcwh = ws + OFF_CWH;
    const u16* wcow = ws + OFF_COW;
    const u16* wgwi = ws + OFF_GWI;
    const u16* wgwh = ws + OFF_GWH;
    const u16* wfw  = ws + OFF_FW;

    const int l = threadIdx.x & 63;
    const int w = threadIdx.x >> 6;
    const int wr = (w >> 2) << 5;
    const int wc = (w & 3) << 6;
    const int rb = (l >> 4) << 2;
    const int c15 = l & 15;

    const int AcCon[8] = {896, 960, 768, 832, 512, 576, 640, 704};   // x|fac|h_con
    const int AcGen[8] = {0, 64, 128, 192, 256, 320, 384, 448};      // h_gen

    // ------------------------------ con r ----------------------------------
    {
        const u16* Wp[8]; int Wld[8];
#pragma unroll
        for (int t = 0; t < 4; ++t) { Wp[t] = wcw + 65536 + t * 64;  Wld[t] = 256; }
#pragma unroll
        for (int t = 4; t < 8; ++t) { Wp[t] = wcwh + 65536 + (t - 4) * 64; Wld[t] = 256; }
        f32x4 acc[2][4] = {};
        passS256<8>(acc, SA, SW, panel, AcCon, Wp, Wld);
#pragma unroll
        for (int f = 0; f < 2; ++f)
#pragma unroll
            for (int j = 0; j < 4; ++j)
#pragma unroll
                for (int t = 0; t < 4; ++t) {
                    int rl = wr + f * 16 + rb + t;
                    int c  = wc + j * 16 + c15;
                    float rv = sigm(acc[f][j][t] + cbih[256 + c] + cbhh[256 + c]);
                    float hv = bf2f(panel[(size_t)rl * 1024 + 512 + c]);
                    ldsw16(R0 + (c >> 6) * 8192, rl, c & 63, f2bf(rv * hv));  // rh_C
                }
        __syncthreads();
    }
    // ------------------------- con z + con n --------------------------------
    {
        f32x4 aZ[2][4] = {};
        {
            const u16* Wp[8]; int Wld[8];
#pragma unroll
            for (int t = 0; t < 4; ++t) { Wp[t] = wcw + t * 64;  Wld[t] = 256; }
#pragma unroll
            for (int t = 4; t < 8; ++t) { Wp[t] = wcwh + (t - 4) * 64; Wld[t] = 256; }
            passS256<8>(aZ, SA, SW, panel, AcCon, Wp, Wld);
        }
        f32x4 aN[2][4] = {};
        {
            const int Ac4[4] = {896, 960, 768, 832};                 // x|factor
            const u16* Wp0[4]; int Wl0[4];
#pragma unroll
            for (int t = 0; t < 4; ++t) { Wp0[t] = wcw + 131072 + t * 64; Wl0[t] = 256; }
            passS256<4>(aN, SA, SW, panel, Ac4, Wp0, Wl0);
            const char* Ares[4] = {R0, R0 + 8192, R0 + 16384, R0 + 24576}; // rh_C
            const u16* Wp1[4]; int Wl1[4];
#pragma unroll
            for (int t = 0; t < 4; ++t) { Wp1[t] = wcwh + 131072 + t * 64; Wl1[t] = 256; }
            passR256<4>(aN, SW, Ares, Wp1, Wl1);
        }
#pragma unroll
        for (int f = 0; f < 2; ++f)
#pragma unroll
            for (int j = 0; j < 4; ++j)
#pragma unroll
                for (int t = 0; t < 4; ++t) {
                    int rl = wr + f * 16 + rb + t;
                    int c  = wc + j * 16 + c15;
                    float zv = sigm(aZ[f][j][t] + cbih[c] + cbhh[c]);
                    float nv = tanhf(aN[f][j][t] + cbih[512 + c] + cbhh[512 + c]);
                    float hv = bf2f(panel[(size_t)rl * 1024 + 512 + c]);
                    float hp = zv * hv + (1.0f - zv) * nv;
                    hp = fminf(fmaxf(hp, -CLIPV), CLIPV);
                    out[(size_t)(row0 + rl) * HD + 512 + c] = hp;           // con_state
                    ldsw16(R0 + 32768 + (c >> 6) * 8192, rl, c & 63, f2bf(hp)); // cs
                }
        __syncthreads();
    }
    // --------------------------------- co -----------------------------------
    {
        const char* Ares[4] = {R0 + 32768, R0 + 40960, R0 + 49152, R0 + 57344};
        const u16* Wp[4]; int Wld[4];
#pragma unroll
        for (int t = 0; t < 4; ++t) { Wp[t] = wcow + t * 64; Wld[t] = 256; }
        f32x4 acc[2][4] = {};
        passR256<4>(acc, SW, Ares, Wp, Wld);
#pragma unroll
        for (int f = 0; f < 2; ++f)
#pragma unroll
            for (int j = 0; j < 4; ++j)
#pragma unroll
                for (int t = 0; t < 4; ++t) {
                    int rl = wr + f * 16 + rb + t;
                    int c  = wc + j * 16 + c15;
                    float v = acc[f][j][t] + cob[c];
                    if (c < 128) {
                        out[(size_t)(row0 + rl) * HD + 1024 + c] = v;   // gen_input
                        out[(size_t)(row0 + rl) * HD + 768 + c]  = v;   // co_mean
                        ldsw16(R1 + (c >> 6) * 8192, rl, c & 63, f2bf(v)); // gi
                    } else {
                        out[(size_t)(row0 + rl) * HD + 896 + (c - 128)] = v; // logstd
                    }
                }
        __syncthreads();
    }
    // ------------------------------ gen r -----------------------------------
    const char* Agi[2] = {R1, R1 + 8192};
    for (int cc = 0; cc < 2; ++cc) {
        f32x4 acc[2][4] = {};
        {
            const u16* Wp0[2] = {wgwi + (size_t)(512 + cc * 256) * 128,
                                 wgwi + (size_t)(512 + cc * 256) * 128 + 64};
            const int Wl0[2] = {128, 128};
            passR256<2>(acc, SW, Agi, Wp0, Wl0);
            const u16* Wp1[8]; int Wl1[8];
#pragma unroll
            for (int t = 0; t < 8; ++t) {
                Wp1[t] = wgwh + (size_t)(512 + cc * 256) * 512 + t * 64; Wl1[t] = 512;
            }
            passS256<8>(acc, SA, SW, panel, AcGen, Wp1, Wl1);
        }
#pragma unroll
        for (int f = 0; f < 2; ++f)
#pragma unroll
            for (int j = 0; j < 4; ++j)
#pragma unroll
                for (int t = 0; t < 4; ++t) {
                    int rl = wr + f * 16 + rb + t;
                    int cg = cc * 256 + wc + j * 16 + c15;
                    float rv = sigm(acc[f][j][t] + gbih[512 + cg] + gbhh[512 + cg]);
                    float hv = bf2f(panel[(size_t)rl * 1024 + cg]);
                    ldsw16(R0 + (cg >> 6) * 8192, rl, cg & 63, f2bf(rv * hv)); // rh_G
                }
        __syncthreads();
    }
    // --------------------------- gen z + gen n ------------------------------
    for (int cc = 0; cc < 2; ++cc) {
        f32x4 aZ[2][4] = {};
        {
            const u16* Wp0[2] = {wgwi + (size_t)(cc * 256) * 128,
                                 wgwi + (size_t)(cc * 256) * 128 + 64};
            const int Wl0[2] = {128, 128};
            passR256<2>(aZ, SW, Agi, Wp0, Wl0);
            const u16* Wp1[8]; int Wl1[8];
#pragma unroll
            for (int t = 0; t < 8; ++t) {
                Wp1[t] = wgwh + (size_t)(cc * 256) * 512 + t * 64; Wl1[t] = 512;
            }
            passS256<8>(aZ, SA, SW, panel, AcGen, Wp1, Wl1);
        }
        f32x4 aN[2][4] = {};
        {
            const char* Ares[10] = {R1, R1 + 8192,
                                    R0, R0 + 8192, R0 + 16384, R0 + 24576,
                                    R0 + 32768, R0 + 40960, R0 + 49152, R0 + 57344};
            const u16* Wp[10]; int Wld[10];
            Wp[0] = wgwi + (size_t)(1024 + cc * 256) * 128;       Wld[0] = 128;
            Wp[1] = wgwi + (size_t)(1024 + cc * 256) * 128 + 64;  Wld[1] = 128;
#pragma unroll
            for (int t = 2; t < 10; ++t) {
                Wp[t] = wgwh + (size_t)(1024 + cc * 256) * 512 + (t - 2) * 64; Wld[t] = 512;
            }
            passR256<10>(aN, SW, Ares, Wp, Wld);
        }
#pragma unroll
        for (int f = 0; f < 2; ++f)
#pragma unroll
            for (int j = 0; j < 4; ++j)
#pragma unroll
                for (int t = 0; t < 4; ++t) {
                    int rl = wr + f * 16 + rb + t;
                    int cg = cc * 256 + wc + j * 16 + c15;
                    float zv = sigm(aZ[f][j][t] + gbih[cg] + gbhh[cg]);
                    float nv = tanhf(aN[f][j][t] + gbih[1024 + cg] + gbhh[1024 + cg]);
                    float hv = bf2f(panel[(size_t)rl * 1024 + cg]);
                    float hp = zv * hv + (1.0f - zv) * nv;
                    hp = fminf(fmaxf(hp, -CLIPV), CLIPV);
                    out[(size_t)(row0 + rl) * HD + cg] = hp;                 // gen_state
                    wsw[(size_t)(row0 + rl) * 1024 + 512 + cg] = f2bf(hp);   // gs (panel)
                }
        __syncthreads();
    }
    __threadfence();          // make gs global writes visible (L1 invalidate)
    __syncthreads();
    // -------------------------------- fac -----------------------------------
    {
        const int AcF[8] = {512, 576, 640, 704, 768, 832, 896, 960};  // gs cols
        const u16* Wp[8]; int Wld[8];
#pragma unroll
        for (int t = 0; t < 8; ++t) { Wp[t] = wfw + t * 64; Wld[t] = 512; }
        f32x4 acc[2][2] = {};
        passS128<8>(acc, SA, SW, panel, AcF, Wp, Wld);
        const int wc2 = (w & 3) << 5;
#pragma unroll
        for (int f = 0; f < 2; ++f)
#pragma unroll
            for (int j = 0; j < 2; ++j)
#pragma unroll
                for (int t = 0; t < 4; ++t) {
                    int rl = wr + f * 16 + rb + t;
                    int c  = wc2 + j * 16 + c15;
                    out[(size_t)(row0 + rl) * HD + 1152 + c] = acc[f][j][t];
                }
    }
}

// ===================== preconversion (unchanged, verified) ==================
__global__ __launch_bounds__(256) void k_pre_h(const float* __restrict__ x,
                                               const float* __restrict__ h0,
                                               u16* __restrict__ wsh) {
#pragma unroll
    for (int e = 0; e < 4; ++e) {
        const int q   = blockIdx.x * 1024 + e * 256 + threadIdx.x;
        const int row = q >> 7;
        const int c8  = (q & 127) << 3;
        const float* src;
        if (c8 < 768)      src = h0 + (size_t)row * HD + c8;
        else if (c8 < 896) src = h0 + (size_t)row * HD + c8 + 384;  // factor
        else               src = x + (size_t)row * 128 + (c8 - 896);
        float4 f0 = *(const float4*)(src + 0);
        float4 f1 = *(const float4*)(src + 4);
        const float ff[8] = {f0.x, f0.y, f0.z, f0.w, f1.x, f1.y, f1.z, f1.w};
        s16x8 v;
#pragma unroll
        for (int j = 0; j < 8; ++j) v[j] = (short)f2bf(ff[j]);
        *(s16x8*)(wsh + (size_t)row * 1024 + c8) = v;
    }
}

__global__ __launch_bounds__(256) void k_pre_w(const float* __restrict__ cw,
                                               const float* __restrict__ cwh,
                                               const float* __restrict__ cow,
                                               const float* __restrict__ gwi,
                                               const float* __restrict__ gwh,
                                               u16* __restrict__ dst) {
    const int q = blockIdx.x * 256 + threadIdx.x;
    const size_t eo = (size_t)q * 8;
    const float* src;
    if      (eo < 196608) src = cw  + eo;
    else if (eo < 393216) src = cwh + (eo - 196608);
    else if (eo < 458752) src = cow + (eo - 393216);
    else if (eo < 655360) src = gwi + (eo - 458752);
    else                  src = gwh + (eo - 655360);
    float4 f0 = *(const float4*)(src + 0);
    float4 f1 = *(const float4*)(src + 4);
    const float ff[8] = {f0.x, f0.y, f0.z, f0.w, f1.x, f1.y, f1.z, f1.w};
    s16x8 v;
#pragma unroll
    for (int j = 0; j < 8; ++j) v[j] = (short)f2bf(ff[j]);
    *(s16x8*)(dst + eo) = v;
}

__global__ __launch_bounds__(256) void k_pre_fw(const float* __restrict__ fw,
                                                u16* __restrict__ dst) {
    const int col = blockIdx.x * 256 + threadIdx.x;
    float s = 0.f;
    for (int r = 0; r < 128; ++r) {
        float a = fw[r * 512 + col];
        s = fmaf(a, a, s);
    }
    const float inv = 1.0f / fmaxf(sqrtf(s), 1e-12f);
    for (int r = 0; r < 128; ++r)
        dst[r * 512 + col] = f2bf(fw[r * 512 + col] * inv);
}

// ===================== fallback path (no usable ws) =========================
// Round-5/6 verified LDS drain kernels, f32 staging, 256 threads.
struct KSrc {
    const void* p[5];
    int ld[5];
    int kind[5];
    const float* scale;
};

template <int R>
__device__ __forceinline__ void stage_issue(char* tile, const KSrc& S, int rbase,
                                            int k0, int sIdx, float* regs) {
    const int tid = threadIdx.x;
    if (S.kind[sIdx]) {
        const char* base = (const char*)S.p[sIdx];
        const int w = tid >> 6;
        const size_t ld = (size_t)S.ld[sIdx];
#pragma unroll
        for (int e = 0; e < R / 32; ++e) {
            const int q = e * 256 + tid;
            const int r = q >> 3;
            const int b = ((q & 7) << 4) ^ ((r & 7) << 4);
            gll16(base + ((size_t)(rbase + r) * ld + k0) * 2 + b, tile + e * 4096 + w * 1024);
        }
    } else {
        const float* base = (const float*)S.p[sIdx];
        const size_t ld = (size_t)S.ld[sIdx];
#pragma unroll
        for (int e = 0; e < R / 64; ++e) {
            const int q = e * 256 + tid;
            const int r = q >> 2;
            const int kloc = (q & 3) << 4;
            const float* pp = base + (size_t)(rbase + r) * ld + k0 + kloc;
            float* d = regs + e * 16;
            *(float4*)(d + 0)  = *(const float4*)(pp + 0);
            *(float4*)(d + 4)  = *(const float4*)(pp + 4);
            *(float4*)(d + 8)  = *(const float4*)(pp + 8);
            *(float4*)(d + 12) = *(const float4*)(pp + 12);
        }
    }
}

template <int R>
__device__ __forceinline__ void stage_write(char* tile, const KSrc& S, int rbase,
                                            int k0, int sIdx, float* regs) {
    if (S.kind[sIdx]) return;
    const int tid = threadIdx.x;
#pragma unroll
    for (int e = 0; e < R / 64; ++e) {
        const int q = e * 256 + tid;
        const int r = q >> 2;
        float* ff = regs + e * 16;
        if (S.scale) {
            const int kabs = k0 + ((q & 3) << 4);
#pragma unroll
            for (int j = 0; j < 16; ++j) ff[j] *= S.scale[kabs + j];
        }
        s16x8 v0, v1;
#pragma unroll
        for (int j = 0; j < 8; ++j) {
            v0[j] = (short)f2bf(ff[j]);
            v1[j] = (short)f2bf(ff[j + 8]);
        }
        const int swz = (r & 7) << 4;
        *(s16x8*)(tile + r * 128 + ((((q & 3) << 5) + 0)  ^ swz)) = v0;
        *(s16x8*)(tile + r * 128 + ((((q & 3) << 5) + 16) ^ swz)) = v1;
    }
}

__device__ __forceinline__ void cmp64_4w(f32x4 (&acc)[2][4], const char* At, const char* Wt) {
    const int l = threadIdx.x & 63, w = threadIdx.x >> 6;
    const int wr = (w >> 1) << 5, wc = (w & 1) << 6;
    const int g = l >> 4, r15 = l & 15;
#pragma unroll
    for (int ks = 0; ks < 2; ++ks) {
        bf16x8 a[2], b[4];
#pragma unroll
        for (int f = 0; f < 2; ++f) a[f] = ldfrag(At, wr + f * 16 + r15, ks, g);
#pragma unroll
        for (int f = 0; f < 4; ++f) b[f] = ldfrag(Wt, wc + f * 16 + r15, ks, g);
#pragma unroll
        for (int i = 0; i < 2; ++i)
#pragma unroll
            for (int j = 0; j < 4; ++j)
                acc[i][j] = __builtin_amdgcn_mfma_f32_16x16x32_bf16(a[i], b[j], acc[i][j], 0, 0, 0);
    }
}

template <int NT>
__device__ __forceinline__ void gemm1(f32x4 (&acc)[2][4], char* At, char* Wt,
                                      const KSrc& A, const KSrc& W,
                                      int row0, int col0) {
    float ra[16], rw[32];
#pragma unroll
    for (int kt = 0; kt < NT; ++kt) {
        const int s = kt >> 1;
        __syncthreads();
        stage_issue<64> (At, A, row0, kt * 64, s, ra);
        stage_issue<128>(Wt, W, col0, kt * 64, s, rw);
        stage_write<64> (At, A, row0, kt * 64, s, ra);
        stage_write<128>(Wt, W, col0, kt * 64, s, rw);
        __syncthreads();
        cmp64_4w(acc, At, Wt);
    }
}

#define FB_SHARED __shared__ alignas(16) char At[8192], Wt[16384];
#define FB_IDX                                                              \
    const int l  = threadIdx.x & 63;                                        \
    const int w  = threadIdx.x >> 6;                                        \
    const int wr = (w >> 1) << 5;                                           \
    const int wc = (w & 1) << 6;

__global__ __launch_bounds__(256) void f_con_r(
    const float* __restrict__ x, const float* __restrict__ h0,
    const float* __restrict__ wih, const float* __restrict__ bih,
    const float* __restrict__ whh, const float* __restrict__ bhh,
    float* __restrict__ out) {
    FB_SHARED
    const int lb = xswz();
    const int col0 = (lb & 1) * 128;
    const int row0 = (lb >> 1) * 64;
    KSrc A = {{x, h0 + 1024, h0 + 256, h0 + 256, nullptr},
              {128, HD, HD, HD, 0}, {0, 0, 0, 0, 0}, nullptr};
    KSrc W = {{wih + 65536, wih + 65536, whh + 65536 - 256, whh + 65536 - 256, nullptr},
              {256, 256, 256, 256, 0}, {0, 0, 0, 0, 0}, nullptr};
    f32x4 acc[2][4] = {};
    gemm1<8>(acc, At, Wt, A, W, row0, col0);
    FB_IDX
    u16* outs = (u16*)out;
#pragma unroll
    for (int i = 0; i < 2; ++i)
#pragma unroll
        for (int j = 0; j < 4; ++j)
#pragma unroll
            for (int t = 0; t < 4; ++t) {
                int row = row0 + wr + i * 16 + (l >> 4) * 4 + t;
                int c   = col0 + wc + j * 16 + (l & 15);
                float rv = sigm(acc[i][j][t] + bih[256 + c] + bhh[256 + c]);
                float hv = h0[(size_t)row * HD + 512 + c];
                outs[(size_t)row * 2560 + 512 + c] = f2bf(rv * hv);
            }
}

__global__ __launch_bounds__(256) void f_con_zn(
    const float* __restrict__ x, const float* __restrict__ h0,
    const float* __restrict__ wih, const float* __restrict__ bih,
    const float* __restrict__ whh, const float* __restrict__ bhh,
    float* __restrict__ out) {
    FB_SHARED
    const int lb = xswz();
    const int col0 = (lb & 1) * 128;
    const int row0 = (lb >> 1) * 64;
    const u16* outs = (const u16*)out;
    KSrc Az = {{x, h0 + 1024, h0 + 256, h0 + 256, nullptr},
               {128, HD, HD, HD, 0}, {0, 0, 0, 0, 0}, nullptr};
    KSrc Wz = {{wih, wih, whh - 256, whh - 256, nullptr},
               {256, 256, 256, 256, 0}, {0, 0, 0, 0, 0}, nullptr};
    KSrc An = {{x, h0 + 1024, outs + 256, outs + 256, nullptr},
               {128, HD, 2560, 2560, 0}, {0, 0, 1, 1, 0}, nullptr};
    KSrc Wn = {{wih + 512 * 256, wih + 512 * 256,
                whh + 512 * 256 - 256, whh + 512 * 256 - 256, nullptr},
               {256, 256, 256, 256, 0}, {0, 0, 0, 0, 0}, nullptr};
    f32x4 aZ[2][4] = {}, aN[2][4] = {};
    gemm1<8>(aZ, At, Wt, Az, Wz, row0, col0);
    gemm1<8>(aN, At, Wt, An, Wn, row0, col0);
    FB_IDX
#pragma unroll
    for (int i = 0; i < 2; ++i)
#pragma unroll
        for (int j = 0; j < 4; ++j)
#pragma unroll
            for (int t = 0; t < 4; ++t) {
                int row = row0 + wr + i * 16 + (l >> 4) * 4 + t;
                int c   = col0 + wc + j * 16 + (l & 15);
                float zv = sigm(aZ[i][j][t] + bih[c] + bhh[c]);
                float nv = tanhf(aN[i][j][t] + bih[512 + c] + bhh[512 + c]);
                float hv = h0[(size_t)row * HD + 512 + c];
                float hp = zv * hv + (1.0f - zv) * nv;
                out[(size_t)row * HD + 512 + c] = fminf(fmaxf(hp, -CLIPV), CLIPV);
            }
}

__global__ __launch_bounds__(256) void f_co(
    const float* __restrict__ cw, const float* __restrict__ cb,
    float* __restrict__ out) {
    FB_SHARED
    const int lb = xswz();
    const int col0 = (lb & 1) * 128;
    const int row0 = (lb >> 1) * 64;
    KSrc A = {{out + 512, out + 512, nullptr, nullptr, nullptr},
              {HD, HD, 0, 0, 0}, {0, 0, 0, 0, 0}, nullptr};
    KSrc W = {{cw, cw, nullptr, nullptr, nullptr},
              {256, 256, 0, 0, 0}, {0, 0, 0, 0, 0}, nullptr};
    f32x4 acc[2][4] = {};
    gemm1<4>(acc, At, Wt, A, W, row0, col0);
    FB_IDX
    u16* outw = (u16*)out;
#pragma unroll
    for (int i = 0; i < 2; ++i)
#pragma unroll
        for (int j = 0; j < 4; ++j)
#pragma unroll
            for (int t = 0; t < 4; ++t) {
                int row = row0 + wr + i * 16 + (l >> 4) * 4 + t;
                int c   = col0 + wc + j * 16 + (l & 15);
                float v = acc[i][j][t] + cb[c];
                if (c < 128) {
                    out[(size_t)row * HD + 1024 + c]    = v;
                    outw[(size_t)row * 2560 + 2304 + c] = f2bf(v);
                }
            }
}

__global__ __launch_bounds__(256) void f_gen_r(
    const float* __restrict__ h0,
    const float* __restrict__ wih, const float* __restrict__ bih,
    const float* __restrict__ whh, const float* __restrict__ bhh,
    float* __restrict__ out) {
    FB_SHARED
    const int lb = xswz();
    const int col0 = (lb & 3) * 128;
    const int row0 = (lb >> 2) * 64;
    const u16* outs = (const u16*)out;
    KSrc A = {{outs + 2304, h0 - 128, h0 - 128, h0 - 128, h0 - 128},
              {2560, HD, HD, HD, HD}, {1, 0, 0, 0, 0}, nullptr};
    KSrc W = {{wih + 65536, whh + 512 * 512 - 128, whh + 512 * 512 - 128,
               whh + 512 * 512 - 128, whh + 512 * 512 - 128},
              {128, 512, 512, 512, 512}, {0, 0, 0, 0, 0}, nullptr};
    f32x4 acc[2][4] = {};
    gemm1<10>(acc, At, Wt, A, W, row0, col0);
    FB_IDX
    u16* outw = (u16*)out;
#pragma unroll
    for (int i = 0; i < 2; ++i)
#pragma unroll
        for (int j = 0; j < 4; ++j)
#pragma unroll
            for (int t = 0; t < 4; ++t) {
                int row = row0 + wr + i * 16 + (l >> 4) * 4 + t;
                int c   = col0 + wc + j * 16 + (l & 15);
                float rv = sigm(acc[i][j][t] + bih[512 + c] + bhh[512 + c]);
                float hv = h0[(size_t)row * HD + c];
                outw[(size_t)row * 2560 + 1536 + c] = f2bf(rv * hv);
            }
}

__global__ __launch_bounds__(256) void f_gen_zn(
    const float* __restrict__ h0,
    const float* __restrict__ wih, const float* __restrict__ bih,
    const float* __restrict__ whh, const float* __restrict__ bhh,
    float* __restrict__ out) {
    FB_SHARED
    const int lb = xswz();
    const int col0 = (lb & 3) * 128;
    const int row0 = (lb >> 2) * 64;
    const u16* outs = (const u16*)out;
    KSrc Az = {{outs + 2304, h0 - 128, h0 - 128, h0 - 128, h0 - 128},
               {2560, HD, HD, HD, HD}, {1, 0, 0, 0, 0}, nullptr};
    KSrc Wz = {{wih, whh - 128, whh - 128, whh - 128, whh - 128},
               {128, 512, 512, 512, 512}, {0, 0, 0, 0, 0}, nullptr};
    KSrc An = {{outs + 2304, outs + 1408, outs + 1408, outs + 1408, outs + 1408},
               {2560, 2560, 2560, 2560, 2560}, {1, 1, 1, 1, 1}, nullptr};
    KSrc Wn = {{wih + 1024 * 128, whh + 1024 * 512 - 128, whh + 1024 * 512 - 128,
                whh + 1024 * 512 - 128, whh + 1024 * 512 - 128},
               {128, 512, 512, 512, 512}, {0, 0, 0, 0, 0}, nullptr};
    f32x4 aZ[2][4] = {}, aN[2][4] = {};
    gemm1<10>(aZ, At, Wt, Az, Wz, row0, col0);
    gemm1<10>(aN, At, Wt, An, Wn, row0, col0);
    FB_IDX
#pragma unroll
    for (int i = 0; i < 2; ++i)
#pragma unroll
        for (int j = 0; j < 4; ++j)
#pragma unroll
            for (int t = 0; t < 4; ++t) {
                int row = row0 + wr + i * 16 + (l >> 4) * 4 + t;
                int c   = col0 + wc + j * 16 + (l & 15);
                float zv = sigm(aZ[i][j][t] + bih[c] + bhh[c]);
                float nv = tanhf(aN[i][j][t] + bih[1024 + c] + bhh[1024 + c]);
                float hv = h0[(size_t)row * HD + c];
                float hp = zv * hv + (1.0f - zv) * nv;
                out[(size_t)row * HD + c] = fminf(fmaxf(hp, -CLIPV), CLIPV);
            }
}

__global__ __launch_bounds__(256) void f_fac(
    const float* __restrict__ fw, float* __restrict__ out) {
    FB_SHARED
    __shared__ float invn[512];
    const int row0 = xswz() * 64;
    {
        const int t = threadIdx.x;
        float s0 = 0.f, s1 = 0.f;
        for (int r = 0; r < 128; ++r) {
            float a0 = fw[r * 512 + t];
            float a1 = fw[r * 512 + t + 256];
            s0 = fmaf(a0, a0, s0);
            s1 = fmaf(a1, a1, s1);
        }
        invn[t]       = 1.0f / fmaxf(sqrtf(s0), 1e-12f);
        invn[t + 256] = 1.0f / fmaxf(sqrtf(s1), 1e-12f);
        __syncthreads();
    }
    KSrc A = {{out, out, out, out, nullptr},
              {HD, HD, HD, HD, 0}, {0, 0, 0, 0, 0}, nullptr};
    KSrc W = {{fw, fw, fw, fw, nullptr},
              {512, 512, 512, 512, 0}, {0, 0, 0, 0, 0}, invn};
    f32x4 acc[2][4] = {};
    gemm1<8>(acc, At, Wt, A, W, row0, 0);
    FB_IDX
#pragma unroll
    for (int i = 0; i < 2; ++i)
#pragma unroll
        for (int j = 0; j < 4; ++j)
#pragma unroll
            for (int t = 0; t < 4; ++t) {
                int row = row0 + wr + i * 16 + (l >> 4) * 4 + t;
                int c   = wc + j * 16 + (l & 15);
                out[(size_t)row * HD + 1152 + c] = acc[i][j][t];
            }
}

__global__ __launch_bounds__(256) void f_co_fin(
    const float* __restrict__ cw, const float* __restrict__ cb,
    float* __restrict__ out) {
    FB_SHARED
    const int row0 = xswz() * 64;
    KSrc A = {{out + 512, out + 512, nullptr, nullptr, nullptr},
              {HD, HD, 0, 0, 0}, {0, 0, 0, 0, 0}, nullptr};
    KSrc W = {{cw + 128 * 256, cw + 128 * 256, nullptr, nullptr, nullptr},
              {256, 256, 0, 0, 0}, {0, 0, 0, 0, 0}, nullptr};
    f32x4 acc[2][4] = {};
    gemm1<4>(acc, At, Wt, A, W, row0, 0);
    FB_IDX
#pragma unroll
    for (int i = 0; i < 2; ++i)
#pragma unroll
        for (int j = 0; j < 4; ++j)
#pragma unroll
            for (int t = 0; t < 4; ++t) {
                int row = row0 + wr + i * 16 + (l >> 4) * 4 + t;
                int c   = wc + j * 16 + (l & 15);
                out[(size_t)row * HD + 896 + c] = acc[i][j][t] + cb[128 + c];
            }
#pragma unroll
    for (int e = 0; e < 8; ++e) {
        int idx = threadIdx.x + e * 256;
        int r   = idx >> 5;
        int cc  = (idx & 31) << 2;
        *(float4*)&out[(size_t)(row0 + r) * HD + 768 + cc] =
            *(const float4*)&out[(size_t)(row0 + r) * HD + 1024 + cc];
    }
}

// ------------------------------- launch -------------------------------------
extern "C" void kernel_launch(void* const* d_in, const int* in_sizes, int n_in,
                              void* d_out, int out_size, void* d_ws, size_t ws_size,
                              hipStream_t stream) {
    const float* x    = (const float*)d_in[0];
    const float* h0   = (const float*)d_in[1];
    const float* cwih = (const float*)d_in[2];
    const float* cbih = (const float*)d_in[3];
    const float* cwhh = (const float*)d_in[4];
    const float* cbhh = (const float*)d_in[5];
    const float* cow  = (const float*)d_in[6];
    const float* cob  = (const float*)d_in[7];
    const float* gwih = (const float*)d_in[8];
    const float* gbih = (const float*)d_in[9];
    const float* gwhh = (const float*)d_in[10];
    const float* gbhh = (const float*)d_in[11];
    const float* fw   = (const float*)d_in[12];
    float* out = (float*)d_out;
    u16* ws = (u16*)d_ws;

    const bool pre = (ws_size >= (size_t)WS_ELEMS * 2);
    if (pre) {
        k_pre_h <<<2048, 256, 0, stream>>>(x, h0, ws);
        k_pre_w <<<704,  256, 0, stream>>>(cwih, cwhh, cow, gwih, gwhh, ws + OFF_CW);
        k_pre_fw<<<2,    256, 0, stream>>>(fw, ws + OFF_FW);
        k_fused <<<NROW / 64, 512, 0, stream>>>(ws, ws, cbih, cbhh, cob,
                                                gbih, gbhh, out);
    } else {
        f_con_r <<<512,  256, 0, stream>>>(x, h0, cwih, cbih, cwhh, cbhh, out);
        f_con_zn<<<512,  256, 0, stream>>>(x, h0, cwih, cbih, cwhh, cbhh, out);
        f_co    <<<512,  256, 0, stream>>>(cow, cob, out);
        f_gen_r <<<1024, 256, 0, stream>>>(h0, gwih, gbih, gwhh, gbhh, out);
        f_gen_zn<<<1024, 256, 0, stream>>>(h0, gwih, gbih, gwhh, gbhh, out);
        f_fac   <<<256,  256, 0, stream>>>(fw, out);
        f_co_fin<<<256,  256, 0, stream>>>(cow, cob, out);
    }
}